// Round 14
// baseline (1914.037 us; speedup 1.0000x reference)
//
#include <hip/hip_runtime.h>

// Persistent Jacobi: 20 iters = 10 sweeps x 2 fused, one kernel launch.
// Grid-wide sync via a monotonic device-scope atomic ticket barrier
// (no cooperative launch, no per-launch reset needed).
// One wave owns a 4-row band of one image (512 cols = 8 floats/lane).
// b rows live in registers for the whole kernel. Blocks swizzled so each
// XCD owns 2 contiguous images (L2-local ping-pong).
// Co-residency guarantee: 2048 blocks x 1 wave; __launch_bounds__(64,2)
// forces >=2 waves/SIMD => 8 blocks/CU x 256 CU = 2048 all resident.

#define GN 512
#define GB 16
#define HB 4
#define NSWEEP 10
#define BANDS (GN / HB)          // 128 bands per image
#define NBLK (GB * BANDS)        // 2048 blocks, 1 wave each

__device__ unsigned g_ctr = 0;   // monotonic barrier ticket counter

__device__ __forceinline__ void gbarrier() {
    if (threadIdx.x == 0) {
        unsigned t = __hip_atomic_fetch_add(&g_ctr, 1u, __ATOMIC_ACQ_REL,
                                            __HIP_MEMORY_SCOPE_AGENT);
        unsigned target = (t / NBLK + 1u) * NBLK;
        while (__hip_atomic_load(&g_ctr, __ATOMIC_ACQUIRE,
                                 __HIP_MEMORY_SCOPE_AGENT) < target)
            __builtin_amdgcn_s_sleep(4);
    }
    __threadfence();   // all lanes: agent-scope ordering for subsequent loads
}

struct Row { float4 lo, hi; };

__device__ __forceinline__ Row zrow() {
    Row z; z.lo = make_float4(0.f,0.f,0.f,0.f); z.hi = z.lo; return z;
}

__device__ __forceinline__ Row load_row(const float* __restrict__ base, int row, int lane) {
    if ((unsigned)row < GN) {                      // wave-uniform branch
        const float* p = base + row * GN + lane * 8;
        Row r; r.lo = *(const float4*)p; r.hi = *(const float4*)(p + 4);
        return r;
    }
    return zrow();
}

// out = (b + up + dn + left + right) * fac ; fac=0 kills out-of-image rows
__device__ __forceinline__ Row jrow(const Row& up, const Row& cu, const Row& dn,
                                    const Row& bb, float fac, int lane) {
    float lnb = __shfl_up(cu.hi.w, 1);   if (lane == 0)  lnb = 0.f;
    float rnb = __shfl_down(cu.lo.x, 1); if (lane == 63) rnb = 0.f;
    Row o;
    o.lo.x = (bb.lo.x + up.lo.x + dn.lo.x + lnb     + cu.lo.y) * fac;
    o.lo.y = (bb.lo.y + up.lo.y + dn.lo.y + cu.lo.x + cu.lo.z) * fac;
    o.lo.z = (bb.lo.z + up.lo.z + dn.lo.z + cu.lo.y + cu.lo.w) * fac;
    o.lo.w = (bb.lo.w + up.lo.w + dn.lo.w + cu.lo.z + cu.hi.x) * fac;
    o.hi.x = (bb.hi.x + up.hi.x + dn.hi.x + cu.lo.w + cu.hi.y) * fac;
    o.hi.y = (bb.hi.y + up.hi.y + dn.hi.y + cu.hi.x + cu.hi.z) * fac;
    o.hi.z = (bb.hi.z + up.hi.z + dn.hi.z + cu.hi.y + cu.hi.w) * fac;
    o.hi.w = (bb.hi.w + up.hi.w + dn.hi.w + cu.hi.z + rnb    ) * fac;
    return o;
}

__device__ __forceinline__ float facr(int row) {
    return ((unsigned)row < GN) ? 0.25f : 0.f;
}

__global__ __launch_bounds__(64, 2) void jacobi_persist(
    const float* __restrict__ u,
    const float* __restrict__ bvec,
    float* __restrict__ ws,
    float* __restrict__ outp)
{
    const int lane = threadIdx.x;
    const int bid  = blockIdx.x;
    // Remap so each XCD (blockIdx % 8) owns a contiguous band range
    // (= 2 whole images): L2-local sweeps. Bijective since 2048 % 8 == 0.
    const int band = (bid & 7) * (NBLK / 8) + (bid >> 3);
    const int img  = band / BANDS;
    const int R0   = (band % BANDS) * HB;

    const size_t ioff = (size_t)img * (GN * GN);
    const float* bb = bvec + ioff;

    // b rows R0-1 .. R0+4 persist in registers (48 VGPR)
    Row b_m1 = load_row(bb, R0 - 1, lane);
    Row b_0  = load_row(bb, R0,     lane);
    Row b_1  = load_row(bb, R0 + 1, lane);
    Row b_2  = load_row(bb, R0 + 2, lane);
    Row b_3  = load_row(bb, R0 + 3, lane);
    Row b_4  = load_row(bb, R0 + 4, lane);

    const float* src = u + ioff;
    for (int s = 0; s < NSWEEP; ++s) {
        float* dst = ((s & 1) ? outp : ws) + ioff;

        // prologue windows
        Row xm2 = load_row(src, R0 - 2, lane);
        Row xm1 = load_row(src, R0 - 1, lane);
        Row a   = load_row(src, R0,     lane);
        Row c   = load_row(src, R0 + 1, lane);
        Row d   = load_row(src, R0 + 2, lane);

        Row p = jrow(xm2, xm1, a, b_m1, facr(R0 - 1), lane);  // x1[R0-1]
        Row q = jrow(xm1, a,   c, b_0,  0.25f,        lane);  // x1[R0]

        {   // r = R0
            Row e  = load_row(src, R0 + 3, lane);
            Row s1 = jrow(a, c, d, b_1, 0.25f, lane);          // x1[R0+1]
            Row o  = jrow(p, q, s1, b_0, 0.25f, lane);         // x2[R0]
            float* op = dst + (size_t)(R0 + 0) * GN + lane * 8;
            *(float4*)op = o.lo; *(float4*)(op + 4) = o.hi;
            a = c; c = d; d = e; p = q; q = s1;
        }
        {   // r = R0+1
            Row e  = load_row(src, R0 + 4, lane);
            Row s1 = jrow(a, c, d, b_2, 0.25f, lane);
            Row o  = jrow(p, q, s1, b_1, 0.25f, lane);
            float* op = dst + (size_t)(R0 + 1) * GN + lane * 8;
            *(float4*)op = o.lo; *(float4*)(op + 4) = o.hi;
            a = c; c = d; d = e; p = q; q = s1;
        }
        {   // r = R0+2
            Row e  = load_row(src, R0 + 5, lane);
            Row s1 = jrow(a, c, d, b_3, 0.25f, lane);
            Row o  = jrow(p, q, s1, b_2, 0.25f, lane);
            float* op = dst + (size_t)(R0 + 2) * GN + lane * 8;
            *(float4*)op = o.lo; *(float4*)(op + 4) = o.hi;
            a = c; c = d; d = e; p = q; q = s1;
        }
        {   // r = R0+3 (last: r+1 may be out of image)
            Row s1 = jrow(a, c, d, b_4, facr(R0 + 4), lane);
            Row o  = jrow(p, q, s1, b_3, 0.25f, lane);
            float* op = dst + (size_t)(R0 + 3) * GN + lane * 8;
            *(float4*)op = o.lo; *(float4*)(op + 4) = o.hi;
        }

        src = dst;
        if (s != NSWEEP - 1) gbarrier();
    }
}

extern "C" void kernel_launch(void* const* d_in, const int* in_sizes, int n_in,
                              void* d_out, int out_size, void* d_ws, size_t ws_size,
                              hipStream_t stream)
{
    // Inputs: u, b, M_rows, M_cols, M_vals, invD, maxiter
    const float* u    = (const float*)d_in[0];
    const float* bvec = (const float*)d_in[1];
    float* out = (float*)d_out;
    float* ws  = (float*)d_ws;   // 16 MiB used (ping-pong even sweeps)

    jacobi_persist<<<dim3(NBLK), dim3(64), 0, stream>>>(u, bvec, ws, out);
}

// Round 16
// 179.316 us; speedup vs baseline: 10.6741x; 10.6741x over previous
//
#include <hip/hip_runtime.h>

// Jacobi, 5-point Laplacian, N=512, B=16, 20 iters = 10 launches x 2 fused.
// HB=2: one wave computes a 2-row band (512 cols = 8 floats/lane), straight-
// line fused-2. 4096 blocks -> 16 waves/CU (2x Round-10 occupancy: that
// config was latency-bound at 8 waves/CU, 3.9 TB/s of L2-resident traffic).
// Blocks swizzled so each XCD owns contiguous bands (L2-local ping-pong).

#define GN 512
#define GB 16
#define HB 2
#define NLAUNCH 10
#define BANDS (GN / HB)          // 256 bands per image
#define NBLK (GB * BANDS)        // 4096 single-wave blocks

struct Row { float4 lo, hi; };

__device__ __forceinline__ Row zrow() {
    Row z; z.lo = make_float4(0.f,0.f,0.f,0.f); z.hi = z.lo; return z;
}

__device__ __forceinline__ Row load_row(const float* __restrict__ base, int row, int lane) {
    if ((unsigned)row < GN) {                      // wave-uniform branch
        const float* p = base + row * GN + lane * 8;
        Row r; r.lo = *(const float4*)p; r.hi = *(const float4*)(p + 4);
        return r;
    }
    return zrow();
}

// out = (b + up + dn + left + right) * fac ; fac=0 kills out-of-image rows
__device__ __forceinline__ Row jrow(const Row& up, const Row& cu, const Row& dn,
                                    const Row& bb, float fac, int lane) {
    float lnb = __shfl_up(cu.hi.w, 1);   if (lane == 0)  lnb = 0.f;
    float rnb = __shfl_down(cu.lo.x, 1); if (lane == 63) rnb = 0.f;
    Row o;
    o.lo.x = (bb.lo.x + up.lo.x + dn.lo.x + lnb     + cu.lo.y) * fac;
    o.lo.y = (bb.lo.y + up.lo.y + dn.lo.y + cu.lo.x + cu.lo.z) * fac;
    o.lo.z = (bb.lo.z + up.lo.z + dn.lo.z + cu.lo.y + cu.lo.w) * fac;
    o.lo.w = (bb.lo.w + up.lo.w + dn.lo.w + cu.lo.z + cu.hi.x) * fac;
    o.hi.x = (bb.hi.x + up.hi.x + dn.hi.x + cu.lo.w + cu.hi.y) * fac;
    o.hi.y = (bb.hi.y + up.hi.y + dn.hi.y + cu.hi.x + cu.hi.z) * fac;
    o.hi.z = (bb.hi.z + up.hi.z + dn.hi.z + cu.hi.y + cu.hi.w) * fac;
    o.hi.w = (bb.hi.w + up.hi.w + dn.hi.w + cu.hi.z + rnb    ) * fac;
    return o;
}

__device__ __forceinline__ float facr(int row) {
    return ((unsigned)row < GN) ? 0.25f : 0.f;
}

__global__ __launch_bounds__(64, 4) void jacobi2_h2(
    const float* __restrict__ xin,
    const float* __restrict__ bvec,
    float* __restrict__ xout)
{
    const int lane = threadIdx.x;
    const int bid  = blockIdx.x;
    // XCD-contiguous remap (bijective: 4096 % 8 == 0): each XCD owns 2 images.
    const int band = (bid & 7) * (NBLK / 8) + (bid >> 3);
    const int img  = band / BANDS;
    const int R0   = (band % BANDS) * HB;

    const size_t ioff = (size_t)img * (GN * GN);
    const float* x0 = xin  + ioff;
    const float* bb = bvec + ioff;

    // x0 rows R0-2 .. R0+3
    Row xm2 = load_row(x0, R0 - 2, lane);
    Row xm1 = load_row(x0, R0 - 1, lane);
    Row a   = load_row(x0, R0,     lane);
    Row c   = load_row(x0, R0 + 1, lane);
    Row d   = load_row(x0, R0 + 2, lane);
    Row e   = load_row(x0, R0 + 3, lane);

    // b rows R0-1 .. R0+2
    Row bm1 = load_row(bb, R0 - 1, lane);
    Row b0  = load_row(bb, R0,     lane);
    Row b1  = load_row(bb, R0 + 1, lane);
    Row b2  = load_row(bb, R0 + 2, lane);

    // x1 rows R0-1 .. R0+2   (R0+1 <= 511 always => fac 0.25)
    Row p  = jrow(xm2, xm1, a, bm1, facr(R0 - 1), lane);
    Row q  = jrow(xm1, a,   c, b0,  0.25f,        lane);
    Row s1 = jrow(a,   c,   d, b1,  0.25f,        lane);
    Row s2 = jrow(c,   d,   e, b2,  facr(R0 + 2), lane);

    // x2 rows R0, R0+1
    Row o0 = jrow(p, q,  s1, b0, 0.25f, lane);
    Row o1 = jrow(q, s1, s2, b1, 0.25f, lane);

    float* op = xout + ioff + (size_t)R0 * GN + lane * 8;
    *(float4*)op       = o0.lo;
    *(float4*)(op + 4) = o0.hi;
    op += GN;
    *(float4*)op       = o1.lo;
    *(float4*)(op + 4) = o1.hi;
}

extern "C" void kernel_launch(void* const* d_in, const int* in_sizes, int n_in,
                              void* d_out, int out_size, void* d_ws, size_t ws_size,
                              hipStream_t stream)
{
    // Inputs: u, b, M_rows, M_cols, M_vals, invD, maxiter
    const float* u    = (const float*)d_in[0];
    const float* bvec = (const float*)d_in[1];
    float* out = (float*)d_out;
    float* ws  = (float*)d_ws;   // 16 MiB used

    // 10 launches; even idx -> ws, odd -> out; idx 9 lands in d_out.
    const float* src = u;
    for (int k = 0; k < NLAUNCH; ++k) {
        float* dst = (k & 1) ? out : ws;
        jacobi2_h2<<<dim3(NBLK), dim3(64), 0, stream>>>(src, bvec, dst);
        src = dst;
    }
}